// Round 2
// baseline (348.175 us; speedup 1.0000x reference)
//
#include <hip/hip_runtime.h>
#include <math.h>

#define T_TOTAL 16384
#define HDIM    2048
#define NEXP    64

// ---------------------------------------------------------------------------
// Register-tile GEMM, no LDS, no barriers.
//   partial[t][ks][e] = sum_{k in slice ks} x[t][k] * w[e][k]
// Block: 256 threads = 4 waves, TM=256 tokens x 64 experts.
// Thread: 8 tokens x 8 experts (64 acc VGPRs), K advanced 4 at a time (float4).
// Within a wave, 8 lanes share each X address and 8 lanes share each W
// address -> the coalescer dedups them to one L1 request; LDS staging would
// add barriers + bank conflicts for zero traffic reduction.
// ---------------------------------------------------------------------------
template<int KS>
__global__ __launch_bounds__(256)
void router_gemm_kernel(const float* __restrict__ x,
                        const float* __restrict__ w,
                        float* __restrict__ partial)
{
    constexpr int KSLICE = HDIM / KS;

    const int tid = threadIdx.x;
    const int tb  = blockIdx.x & 63;     // token block (64 blocks of 256 tokens)
    const int ks  = blockIdx.x >> 6;     // k-slice 0..KS-1
    const int t0  = tb * 256;
    const int k0  = ks * KSLICE;

    const int tg  = tid >> 3;            // 0..31 : tokens t0+tg*8 .. +7
    const int eg  = tid & 7;             // 0..7  : experts eg*8 .. +7

    // Hoisted row pointers: inner loop uses only immediate offsets
    // (kc*4 <= 508 bytes for KS=16, fits global_load 13-bit signed imm).
    const float* xp[8];
    const float* wp[8];
    {
        const float* xb = x + (size_t)(t0 + tg * 8) * HDIM + k0;
        const float* wb = w + (size_t)(eg * 8) * HDIM + k0;
#pragma unroll
        for (int i = 0; i < 8; ++i) xp[i] = xb + (size_t)i * HDIM;
#pragma unroll
        for (int j = 0; j < 8; ++j) wp[j] = wb + (size_t)j * HDIM;
    }

    float acc[8][8];
#pragma unroll
    for (int i = 0; i < 8; ++i)
#pragma unroll
        for (int j = 0; j < 8; ++j) acc[i][j] = 0.0f;

#pragma unroll 1
    for (int kc = 0; kc < KSLICE; kc += 4) {
        float4 xv[8], wv[8];
#pragma unroll
        for (int i = 0; i < 8; ++i) xv[i] = *(const float4*)(xp[i] + kc);
#pragma unroll
        for (int j = 0; j < 8; ++j) wv[j] = *(const float4*)(wp[j] + kc);
#pragma unroll
        for (int i = 0; i < 8; ++i)
#pragma unroll
            for (int j = 0; j < 8; ++j) {
                acc[i][j] = fmaf(xv[i].x, wv[j].x, acc[i][j]);
                acc[i][j] = fmaf(xv[i].y, wv[j].y, acc[i][j]);
                acc[i][j] = fmaf(xv[i].z, wv[j].z, acc[i][j]);
                acc[i][j] = fmaf(xv[i].w, wv[j].w, acc[i][j]);
            }
    }

    // partial layout [t][ks][e] -> top-k reads each token's KS*64 floats
    // contiguously, fully coalesced.
    float* pp = partial + ((size_t)(t0 + tg * 8) * KS + ks) * NEXP + eg * 8;
#pragma unroll
    for (int i = 0; i < 8; ++i) {
        float* q = pp + (size_t)i * KS * NEXP;
        *(float4*)(q)     = make_float4(acc[i][0], acc[i][1], acc[i][2], acc[i][3]);
        *(float4*)(q + 4) = make_float4(acc[i][4], acc[i][5], acc[i][6], acc[i][7]);
    }
}

// ---------------------------------------------------------------------------
// Sum KS partials + sigmoid + biased top-8 (desc, ties -> lower idx) +
// renorm * 2.5. One wave per token, lane = expert.
// ---------------------------------------------------------------------------
__global__ __launch_bounds__(256)
void router_topk_kernel(const float* __restrict__ partial,
                        const float* __restrict__ bias,
                        float* __restrict__ out_scores,
                        float* __restrict__ out_idx,
                        int ksCount)
{
    const int token = blockIdx.x * 4 + (threadIdx.x >> 6);
    const int lane  = threadIdx.x & 63;

    const float* pt = partial + (size_t)token * ksCount * NEXP + lane;
    float logit = 0.0f;
    for (int s = 0; s < ksCount; ++s) logit += pt[(size_t)s * NEXP];

    const float score = 1.0f / (1.0f + expf(-logit));
    float key = score + bias[lane];

    float myscore = 0.0f;
    int   myidx   = 0;
    float denom   = 0.0f;

#pragma unroll
    for (int r = 0; r < 8; ++r) {
        float bk = key;
        int   bi = lane;
#pragma unroll
        for (int off = 32; off > 0; off >>= 1) {
            const float ok = __shfl_xor(bk, off);
            const int   oi = __shfl_xor(bi, off);
            if (ok > bk || (ok == bk && oi < bi)) { bk = ok; bi = oi; }
        }
        const float wsc = __shfl(score, bi);   // raw (unbiased) winner score
        denom += wsc;
        if (lane == r)  { myscore = wsc; myidx = bi; }
        if (lane == bi) key = -__builtin_inff();
    }

    const float factor = 2.5f / (denom + 1e-20f);
    if (lane < 8) {
        out_scores[(size_t)token * 8 + lane] = myscore * factor;
        out_idx  [(size_t)token * 8 + lane] = (float)myidx;
    }
}

// ---------------------------------------------------------------------------
extern "C" void kernel_launch(void* const* d_in, const int* in_sizes, int n_in,
                              void* d_out, int out_size, void* d_ws, size_t ws_size,
                              hipStream_t stream)
{
    const float* x    = (const float*)d_in[0];   // [4,4096,2048] f32
    const float* bias = (const float*)d_in[1];   // [64] f32
    const float* w    = (const float*)d_in[2];   // [64,2048] f32

    float* out     = (float*)d_out;
    float* partial = (float*)d_ws;

    const size_t bytesPerSlice = (size_t)T_TOTAL * NEXP * 4;   // 4 MiB
    int ksCount;
    if (ws_size >= 16 * bytesPerSlice) {
        ksCount = 16;
        router_gemm_kernel<16><<<dim3(64 * 16), dim3(256), 0, stream>>>(x, w, partial);
    } else if (ws_size >= 8 * bytesPerSlice) {
        ksCount = 8;
        router_gemm_kernel<8><<<dim3(64 * 8), dim3(256), 0, stream>>>(x, w, partial);
    } else {
        ksCount = 4;
        router_gemm_kernel<4><<<dim3(64 * 4), dim3(256), 0, stream>>>(x, w, partial);
    }

    router_topk_kernel<<<dim3(T_TOTAL / 4), dim3(256), 0, stream>>>(
        partial, bias, out, out + (size_t)T_TOTAL * 8, ksCount);
}